// Round 2
// baseline (1971.722 us; speedup 1.0000x reference)
//
#include <hip/hip_runtime.h>

typedef unsigned short u16;
typedef short bf16x8 __attribute__((ext_vector_type(8)));
typedef float f32x4 __attribute__((ext_vector_type(4)));
typedef u16 u16x4v __attribute__((ext_vector_type(4)));

__device__ __forceinline__ float b2f(u16 h){ return __uint_as_float(((unsigned)h)<<16); }
__device__ __forceinline__ u16 f2b(float f){
  unsigned u = __float_as_uint(f);
  u += 0x7fffu + ((u>>16)&1u);
  return (u16)(u>>16);
}
__device__ __forceinline__ float sigm(float x){ return 1.f/(1.f+__expf(-x)); }
__device__ __forceinline__ float tanh_(float x){
  float ax=fabsf(x), e=__expf(-2.f*ax), t=(1.f-e)/(1.f+e);
  return x<0.f? -t : t;
}
__device__ __forceinline__ bf16x8 ld8a(const u16* p){        // 16B-aligned
  union{ u16x4v h[2]; bf16x8 v; } u;
  u.h[0]=*(const u16x4v*)p; u.h[1]=*(const u16x4v*)(p+4); return u.v;
}
__device__ __forceinline__ bf16x8 ld8u(const u16* p){        // 8B-aligned
  union{ u16x4v h[2]; bf16x8 v; } u;
  u.h[0]=*(const u16x4v*)p; u.h[1]=*(const u16x4v*)(p+4); return u.v;
}
__device__ __forceinline__ f32x4 mfma16(bf16x8 a, bf16x8 b, f32x4 c){
  return __builtin_amdgcn_mfma_f32_16x16x32_bf16(a,b,c,0,0,0);
}

// ---------------------------------------------------------------------------
// K0: f32 -> bf16 weight conversion (7 segments), processed in float4 quads.
// ---------------------------------------------------------------------------
struct Cvt7 { const float* src[7]; u16* dst[7]; int cum[8]; };  // cum in quads

__global__ __launch_bounds__(256) void cvt_kernel(Cvt7 a)
{
  const int total = a.cum[7];
  for (int q = blockIdx.x*256 + threadIdx.x; q < total; q += gridDim.x*256){
    int s = 0;
    while (q >= a.cum[s+1]) s++;
    const int off = (q - a.cum[s])*4;
    const float4 v = *(const float4*)(a.src[s] + off);
    u16x4v o; o[0]=f2b(v.x); o[1]=f2b(v.y); o[2]=f2b(v.z); o[3]=f2b(v.w);
    *(u16x4v*)(a.dst[s] + off) = o;
  }
}

// ---------------------------------------------------------------------------
// K1: GRUs. blocks 0..127: sentence GRU (16 sentences each, MFMA). block 128:
// claim GRU (phase A: gi for all t via MFMA; phase B: scalar recurrence) +
// derived constants hc, cvec = hc@Wj[:,:256].T, c0 = hc.Wg_c.
// ---------------------------------------------------------------------------
__global__ __launch_bounds__(256) void gru_kernel(
    const float* __restrict__ claim, const float* __restrict__ sents,
    const float* __restrict__ bihC, const float* __restrict__ bhhC,
    const float* __restrict__ bihS, const float* __restrict__ bhhS,
    const float* __restrict__ WgC,  const float* __restrict__ Wj,
    const u16* __restrict__ WihS_b, const u16* __restrict__ WhhS_b,
    const u16* __restrict__ WihC_b, const u16* __restrict__ WhhC_b,
    float* __restrict__ giC,
    u16* __restrict__ HSout /* HSH base, ld 512 */,
    float* __restrict__ hcf, float* __restrict__ cvec, float* __restrict__ c0p)
{
  __shared__ __align__(16) u16 S16[20480];   // 40 KB
  __shared__ __align__(16) float SF[4096];   // 16 KB
  const int tid = threadIdx.x;
  const f32x4 z4 = {0.f,0.f,0.f,0.f};
  const int w = tid>>6, l = tid&63, ar = l&15, kg8 = (l>>4)*8;

  if (blockIdx.x < 128) {
    u16 (*Xs)[320] = (u16(*)[320])S16;            // 16x320 bf16 x_t tile (padded)
    u16 (*Hb)[256] = (u16(*)[256])(S16 + 5120);   // h bf16 (MFMA A-operand)
    float (*Hf)[256] = (float(*)[256])SF;         // h fp32 carry
    const long i0 = (long)blockIdx.x * 16;
    for (int idx=tid; idx<16*320; idx+=256){ int r=idx/320, c=idx-r*320; Xs[r][c]=0; }
    for (int idx=tid; idx<16*256; idx+=256){ int r=idx>>8, c=idx&255; Hb[r][c]=0; Hf[r][c]=0.f; }
    // gate-aligned columns: wave w owns hidden c in [64w,64w+64); q = s*4+ti
    float bi[3][4], bh[3][4];
    int wOff[12], hOff[12];
    #pragma unroll
    for (int s=0;s<3;s++)
      #pragma unroll
      for (int ti=0;ti<4;ti++){
        int c = w*64 + ti*16 + ar;
        int g = s*256 + c;
        bi[s][ti] = bihS[s*256+c];
        bh[s][ti] = bhhS[s*256+c];
        wOff[s*4+ti] = g*300;
        hOff[s*4+ti] = g*256;
      }
    __syncthreads();

    for (int t=0; t<64; t++){
      for (int idx=tid; idx<16*300; idx+=256){
        int r = idx/300, e = idx - r*300;
        Xs[r][e] = f2b(sents[(i0+r)*19200 + (long)t*300 + e]);
      }
      __syncthreads();
      f32x4 ai[12], ah[12];
      #pragma unroll
      for (int q=0;q<12;q++){ ai[q]=z4; ah[q]=z4; }
      // gi = x_t @ Wih^T  (K=300 padded to 320)
      for (int kc=0; kc<10; kc++){
        bf16x8 a = *(const bf16x8*)&Xs[ar][kc*32 + kg8];
        int kb = kc*32 + kg8;
        #pragma unroll
        for (int q=0;q<12;q++){
          bf16x8 bv;
          if (kb + 8 <= 300) bv = ld8u(WihS_b + wOff[q] + kb);
          else {
            union{ bf16x8 v; u16 u[8]; } tmp;
            #pragma unroll
            for (int j=0;j<8;j++) tmp.u[j] = (kb+j < 300) ? WihS_b[wOff[q]+kb+j] : (u16)0;
            bv = tmp.v;
          }
          ai[q] = mfma16(a, bv, ai[q]);
        }
      }
      // gh = h @ Whh^T  (K=256)
      for (int kc=0; kc<8; kc++){
        bf16x8 a = *(const bf16x8*)&Hb[ar][kc*32 + kg8];
        #pragma unroll
        for (int q=0;q<12;q++){
          bf16x8 bv = ld8a(WhhS_b + hOff[q] + kc*32 + kg8);
          ah[q] = mfma16(a, bv, ah[q]);
        }
      }
      // D layout: col = l&15 (=ar), row = 4*(l>>4)+p
      float hold[4][4];
      #pragma unroll
      for (int ti=0;ti<4;ti++){ int c=w*64+ti*16+ar;
        #pragma unroll
        for (int p=0;p<4;p++) hold[ti][p] = Hf[(l>>4)*4+p][c];
      }
      __syncthreads();
      #pragma unroll
      for (int ti=0;ti<4;ti++){
        int c = w*64 + ti*16 + ar;
        #pragma unroll
        for (int p=0;p<4;p++){
          int rr = (l>>4)*4 + p;
          float r_ = sigm(ai[0*4+ti][p] + bi[0][ti] + ah[0*4+ti][p] + bh[0][ti]);
          float z_ = sigm(ai[1*4+ti][p] + bi[1][ti] + ah[1*4+ti][p] + bh[1][ti]);
          float n_ = tanh_(ai[2*4+ti][p] + bi[2][ti] + r_*(ah[2*4+ti][p] + bh[2][ti]));
          float hn = (1.f - z_)*n_ + z_*hold[ti][p];
          Hf[rr][c] = hn; Hb[rr][c] = f2b(hn);
        }
      }
      __syncthreads();
    }
    for (int idx=tid; idx<16*256; idx+=256){
      int r = idx>>8, c = idx&255;
      HSout[(i0+r)*512 + c] = Hb[r][c];
    }
  } else {
    // ---------------- claim GRU -------------------------------------------
    u16 (*Xc)[320] = (u16(*)[320])S16;   // 64x320 bf16 claim (padded)
    float* hcl = SF;                      // 256 f32 h carry
    // phase A: gi[t][g] = claim @ WihC^T + bihC for all t, via MFMA
    for (int idx=tid; idx<64*320; idx+=256) ((u16*)S16)[idx] = 0;
    __syncthreads();
    for (int idx=tid; idx<64*300; idx+=256){
      int t = idx/300, e = idx - t*300;
      Xc[t][e] = f2b(claim[t*300 + e]);
    }
    __syncthreads();
    for (int cg=0; cg<12; cg++){
      f32x4 acc[4] = {z4,z4,z4,z4};
      for (int kc=0; kc<10; kc++){
        bf16x8 a = *(const bf16x8*)&Xc[w*16 + ar][kc*32 + kg8];
        int kb = kc*32 + kg8;
        #pragma unroll
        for (int ti=0;ti<4;ti++){
          int g = cg*64 + ti*16 + ar;
          bf16x8 bv;
          if (kb + 8 <= 300) bv = ld8u(WihC_b + g*300 + kb);
          else {
            union{ bf16x8 v; u16 u[8]; } tmp;
            #pragma unroll
            for (int j=0;j<8;j++) tmp.u[j] = (kb+j < 300) ? WihC_b[g*300+kb+j] : (u16)0;
            bv = tmp.v;
          }
          acc[ti] = mfma16(a, bv, acc[ti]);
        }
      }
      #pragma unroll
      for (int ti=0;ti<4;ti++){
        int g = cg*64 + ti*16 + ar;
        #pragma unroll
        for (int p=0;p<4;p++)
          giC[(w*16 + (l>>4)*4 + p)*768 + g] = acc[ti][p] + bihC[g];
      }
    }
    // phase B: scalar recurrence, thread c owns hidden unit c
    if (tid < 256) hcl[tid] = 0.f;
    __syncthreads();
    const int c = tid;
    const float bh0 = bhhC[c], bh1 = bhhC[256+c], bh2 = bhhC[512+c];
    const u16* w0p = WhhC_b + (0*256+c)*256;
    const u16* w1p = WhhC_b + (1*256+c)*256;
    const u16* w2p = WhhC_b + (2*256+c)*256;
    for (int t=0;t<64;t++){
      float g0=0.f, g1=0.f, g2=0.f;
      for (int k=0;k<256;k+=4){
        float h0=hcl[k], h1=hcl[k+1], h2=hcl[k+2], h3=hcl[k+3];
        u16x4v a0 = *(const u16x4v*)(w0p+k);
        u16x4v a1 = *(const u16x4v*)(w1p+k);
        u16x4v a2 = *(const u16x4v*)(w2p+k);
        g0 += h0*b2f(a0[0]) + h1*b2f(a0[1]) + h2*b2f(a0[2]) + h3*b2f(a0[3]);
        g1 += h0*b2f(a1[0]) + h1*b2f(a1[1]) + h2*b2f(a1[2]) + h3*b2f(a1[3]);
        g2 += h0*b2f(a2[0]) + h1*b2f(a2[1]) + h2*b2f(a2[2]) + h3*b2f(a2[3]);
      }
      float r_ = sigm(giC[t*768 +       c] + g0 + bh0);
      float z_ = sigm(giC[t*768 + 256 + c] + g1 + bh1);
      float n_ = tanh_(giC[t*768 + 512 + c] + r_*(g2 + bh2));
      float hn = (1.f - z_)*n_ + z_*hcl[c];
      __syncthreads();
      hcl[c] = hn;
      __syncthreads();
    }
    hcf[c] = hcl[c];
    float acc = 0.f;
    for (int k=0;k<256;k++) acc += hcl[k]*Wj[(long)c*1024 + k];
    cvec[c] = acc;
    if (tid==0){ float s=0.f; for (int k=0;k<256;k++) s += hcl[k]*WgC[k]; *c0p = s; }
  }
}

// ---------------------------------------------------------------------------
// K2: gated fusion -> HSg (row-major) and HSgT (transposed, for PV B-operand)
// ---------------------------------------------------------------------------
__global__ __launch_bounds__(256) void fusion_kernel(
    const u16* __restrict__ HSH, const float* __restrict__ Wgs,
    const float* __restrict__ hcf, const float* __restrict__ c0p,
    u16* __restrict__ HSg, u16* __restrict__ HSgT)
{
  __shared__ float gbuf[64];
  __shared__ __align__(16) u16 tile[64][258];
  const int tid=threadIdx.x, w=tid>>6, l=tid&63;
  const long i0 = (long)blockIdx.x * 64;
  const float c0 = *c0p;
  for (int rr=0; rr<16; rr++){
    long i = i0 + w*16 + rr;
    float p = 0.f;
    for (int c=l; c<256; c+=64) p += b2f(HSH[i*512+c]) * Wgs[c];
    for (int o=32;o;o>>=1) p += __shfl_down(p,o,64);
    if (l==0) gbuf[w*16+rr] = sigm(p + c0);
  }
  __syncthreads();
  for (int idx=tid; idx<64*256; idx+=256){
    int r = idx>>8, c = idx&255;
    float g = gbuf[r];
    float hs = b2f(HSH[(i0+r)*512 + c]);
    u16 bv = f2b(g*hs + (1.f-g)*hcf[c]);
    HSg[(i0+r)*256 + c] = bv;
    tile[r][c] = bv;
  }
  __syncthreads();
  const int ioff = tid&63, cg = tid>>6;
  for (int cc=cg; cc<256; cc+=4)
    HSgT[(long)cc*2048 + i0 + ioff] = tile[ioff][cc];
}

// ---------------------------------------------------------------------------
// Generic MFMA GEMM: C[M,N] = A[M,K](bf16) @ Bw[N,K]^T(bf16).  64x64 per block.
// MODE 0: bf16 out (+f32 bias); 1: f32 out; 2: tanh(+bias) -> U triple
// [t, hc*t, |hc-t|]; 3: tanh(+bias) -> bf16.
// ---------------------------------------------------------------------------
template<int MODE>
__global__ __launch_bounds__(256) void gemmk(
    const u16* __restrict__ A, long lda,
    const u16* __restrict__ Bw, long ldb,
    void* __restrict__ Cp, long ldc, int K,
    const float* __restrict__ biasf,
    const float* __restrict__ hc)
{
  const int tid=threadIdx.x, w=tid>>6, l=tid&63, ar=l&15, kg8=(l>>4)*8;
  const long row0 = (long)blockIdx.x*64 + w*16;
  const long col0 = (long)blockIdx.y*64;
  const f32x4 z4 = {0.f,0.f,0.f,0.f};
  f32x4 acc[4] = {z4,z4,z4,z4};
  const u16* ap = A + (row0+ar)*lda + kg8;
  const u16* bp0 = Bw + (col0+ 0+ar)*ldb + kg8;
  const u16* bp1 = Bw + (col0+16+ar)*ldb + kg8;
  const u16* bp2 = Bw + (col0+32+ar)*ldb + kg8;
  const u16* bp3 = Bw + (col0+48+ar)*ldb + kg8;
  for (int k0=0; k0<K; k0+=32){
    bf16x8 a = ld8a(ap + k0);
    acc[0] = mfma16(a, ld8a(bp0+k0), acc[0]);
    acc[1] = mfma16(a, ld8a(bp1+k0), acc[1]);
    acc[2] = mfma16(a, ld8a(bp2+k0), acc[2]);
    acc[3] = mfma16(a, ld8a(bp3+k0), acc[3]);
  }
  const int rbase = (l>>4)*4;
  #pragma unroll
  for (int t=0;t<4;t++){
    long c = col0 + t*16 + ar;
    #pragma unroll
    for (int p=0;p<4;p++){
      long r = row0 + rbase + p;
      float v = acc[t][p];
      if constexpr (MODE==0){
        if (biasf) v += biasf[c];
        ((u16*)Cp)[r*ldc + c] = f2b(v);
      } else if constexpr (MODE==1){
        ((float*)Cp)[r*ldc + c] = v;
      } else if constexpr (MODE==2){
        float tv = tanh_(v + biasf[c]);
        u16* Uo = (u16*)Cp;
        float hv = hc[c];
        Uo[r*768 + c]       = f2b(tv);
        Uo[r*768 + 256 + c] = f2b(hv*tv);
        Uo[r*768 + 512 + c] = f2b(fabsf(hv - tv));
      } else {
        float tv = tanh_(v + biasf[c]);
        ((u16*)Cp)[r*ldc + c] = f2b(tv);
      }
    }
  }
}

// ---------------------------------------------------------------------------
// K5: row softmax on S (f32, ld 2048) -> bf16 P written in place (ld 4096 u16)
// ---------------------------------------------------------------------------
__global__ __launch_bounds__(256) void softmax_rows(float* __restrict__ S)
{
  __shared__ float buf[2048];
  __shared__ float red[4];
  const long i = blockIdx.x;
  float* row = S + i*2048;
  const int tid = threadIdx.x;
  float m = -1e30f;
  for (int c=tid; c<2048; c+=256){ float v=row[c]; buf[c]=v; m=fmaxf(m,v); }
  for (int o=32;o;o>>=1) m = fmaxf(m, __shfl_down(m,o,64));
  if ((tid&63)==0) red[tid>>6] = m;
  __syncthreads();
  m = fmaxf(fmaxf(red[0],red[1]), fmaxf(red[2],red[3]));
  __syncthreads();
  float s = 0.f;
  for (int c=tid; c<2048; c+=256){ float e=__expf(buf[c]-m); buf[c]=e; s+=e; }
  for (int o=32;o;o>>=1) s += __shfl_down(s,o,64);
  if ((tid&63)==0) red[tid>>6] = s;
  __syncthreads();
  s = red[0]+red[1]+red[2]+red[3];
  const float rinv = 1.f/s;
  u16* P = (u16*)S + i*4096;
  for (int c=tid; c<2048; c+=256) P[c] = f2b(buf[c]*rinv);
}

// ---------------------------------------------------------------------------
// K9: entailment attention partials. ae bounded in [-1,1] -> no max-sub needed.
// ---------------------------------------------------------------------------
__global__ __launch_bounds__(256) void ae_kernel(
    const u16* __restrict__ Hcs, const float* __restrict__ Wae, const float* __restrict__ bae,
    float* __restrict__ part, float* __restrict__ psum)
{
  __shared__ float aebuf[64];
  const int b=blockIdx.x, tid=threadIdx.x, w=tid>>6, l=tid&63;
  const long i0 = (long)b*64;
  const float baev = bae[0];
  for (int rr=0; rr<16; rr++){
    long i = i0 + w*16 + rr;
    float p = 0.f;
    for (int c=l; c<256; c+=64) p += b2f(Hcs[i*256+c]) * Wae[c];
    for (int o=32;o;o>>=1) p += __shfl_down(p,o,64);
    if (l==0) aebuf[w*16+rr] = __expf(tanh_(p + baev));
  }
  __syncthreads();
  float acc = 0.f;
  const int c = tid;
  for (int r=0;r<64;r++) acc += aebuf[r] * b2f(Hcs[(i0+r)*256 + c]);
  part[b*256 + c] = acc;
  if (tid==0){ float s=0.f; for (int r=0;r<64;r++) s+=aebuf[r]; psum[b]=s; }
}

__global__ __launch_bounds__(256) void final_kernel(
    const float* __restrict__ part, const float* __restrict__ psum,
    const float* __restrict__ Wf, const float* __restrict__ bf_, float* __restrict__ out)
{
  __shared__ float hbuf[256];
  __shared__ float ssum;
  const int tid = threadIdx.x;
  float v = 0.f;
  for (int b=0;b<32;b++) v += part[b*256 + tid];
  hbuf[tid] = v;
  if (tid==0){ float s=0.f; for (int b=0;b<32;b++) s+=psum[b]; ssum=s; }
  __syncthreads();
  const int w = tid>>6, l = tid&63;
  if (w < 2){
    float rinv = 1.f/ssum;
    float p = 0.f;
    for (int c=l; c<256; c+=64) p += hbuf[c]*rinv*Wf[w*256 + c];
    for (int o=32;o;o>>=1) p += __shfl_down(p,o,64);
    if (l==0) out[w] = sigm(p + bf_[w]);
  }
}

extern "C" void kernel_launch(void* const* d_in, const int* in_sizes, int n_in,
                              void* d_out, int out_size, void* d_ws, size_t ws_size,
                              hipStream_t stream)
{
  const float* claim=(const float*)d_in[0];
  const float* sents=(const float*)d_in[1];
  const float* WihC =(const float*)d_in[2];
  const float* WhhC =(const float*)d_in[3];
  const float* bihC =(const float*)d_in[4];
  const float* bhhC =(const float*)d_in[5];
  const float* WihS =(const float*)d_in[6];
  const float* WhhS =(const float*)d_in[7];
  const float* bihS =(const float*)d_in[8];
  const float* bhhS =(const float*)d_in[9];
  const float* WgS  =(const float*)d_in[10];
  const float* WgC  =(const float*)d_in[11];
  const float* Wac  =(const float*)d_in[12];
  const float* bac  =(const float*)d_in[13];
  // d_in[14] Was, d_in[15] bas: row-constant in scores -> softmax-invariant, unused
  const float* Wext =(const float*)d_in[16];
  const float* bext =(const float*)d_in[17];
  const float* Wj   =(const float*)d_in[18];
  const float* Wae  =(const float*)d_in[19];
  const float* bae  =(const float*)d_in[20];
  const float* Wf   =(const float*)d_in[21];
  const float* bf_  =(const float*)d_in[22];

  char* ws = (char*)d_ws;
  size_t off = 0;
  auto alloc = [&](size_t b)->void*{ void* p = ws + off; off = (off + b + 255) & ~(size_t)255; return p; };
  float* hcf  = (float*)alloc(256*4);
  float* cvec = (float*)alloc(256*4);
  float* c0p  = (float*)alloc(16);
  float* giC  = (float*)alloc((size_t)64*768*4);
  u16* WihS_b = (u16*)alloc((size_t)230400*2);
  u16* WhhS_b = (u16*)alloc((size_t)196608*2);
  u16* WihC_b = (u16*)alloc((size_t)230400*2);
  u16* WhhC_b = (u16*)alloc((size_t)196608*2);
  u16* WacB   = (u16*)alloc((size_t)65536*2);
  u16* WextB  = (u16*)alloc((size_t)131072*2);
  u16* WjB    = (u16*)alloc((size_t)262144*2);
  u16* HSH  = (u16*)alloc((size_t)2048*512*2);   // [HS | H_apo]
  u16* HSg  = (u16*)alloc((size_t)2048*256*2);
  u16* HSgT = (u16*)alloc((size_t)256*2048*2);
  u16* A1   = (u16*)alloc((size_t)2048*256*2);
  u16* Up   = (u16*)alloc((size_t)2048*768*2);   // [Ht | hc*Ht | |hc-Ht|]
  u16* Hcs  = (u16*)alloc((size_t)2048*256*2);
  float* part = (float*)alloc(32*256*4);
  float* psum = (float*)alloc(32*4);
  float* S    = (float*)alloc((size_t)2048*2048*4);  // P(bf16) written in place

  Cvt7 ca;
  const float* srcs[7] = {WihS, WhhS, WihC, WhhC, Wac, Wext, Wj};
  u16* dsts[7] = {WihS_b, WhhS_b, WihC_b, WhhC_b, WacB, WextB, WjB};
  const int ns[7] = {230400,196608,230400,196608,65536,131072,262144};
  int cum = 0;
  for (int i=0;i<7;i++){ ca.src[i]=srcs[i]; ca.dst[i]=dsts[i]; ca.cum[i]=cum; cum += ns[i]/4; }
  ca.cum[7] = cum;
  cvt_kernel<<<(cum+255)/256,256,0,stream>>>(ca);

  gru_kernel<<<129,256,0,stream>>>(claim,sents,bihC,bhhC,bihS,bhhS,WgC,Wj,
                                   WihS_b,WhhS_b,WihC_b,WhhC_b,giC,HSH,hcf,cvec,c0p);
  fusion_kernel<<<32,256,0,stream>>>(HSH,WgS,hcf,c0p,HSg,HSgT);
  // A1 = HSg @ Wac^T + bac
  gemmk<0><<<dim3(32,4),256,0,stream>>>(HSg,256L,WacB,256L,(void*)A1,256L,256,bac,nullptr);
  // S = A1 @ HSg^T   (f32)
  gemmk<1><<<dim3(32,32),256,0,stream>>>(A1,256L,HSg,256L,(void*)S,2048L,256,nullptr,nullptr);
  softmax_rows<<<2048,256,0,stream>>>(S);
  // H_apo = P @ HSg -> HSH[:,256:512]
  gemmk<0><<<dim3(32,4),256,0,stream>>>((const u16*)S,4096L,HSgT,2048L,(void*)(HSH+256),512L,2048,nullptr,nullptr);
  // H_tilde = tanh(HSH @ Wext^T + bext) -> U triple
  gemmk<2><<<dim3(32,4),256,0,stream>>>(HSH,512L,WextB,512L,(void*)Up,768L,512,bext,hcf);
  // H_c_s = tanh(U @ Wj[:,256:]^T + cvec)
  gemmk<3><<<dim3(32,4),256,0,stream>>>(Up,768L,WjB+256,1024L,(void*)Hcs,256L,768,cvec,nullptr);
  ae_kernel<<<32,256,0,stream>>>(Hcs,Wae,bae,part,psum);
  final_kernel<<<1,256,0,stream>>>(part,psum,Wf,bf_,(float*)d_out);
}